// Round 5
// baseline (284.827 us; speedup 1.0000x reference)
//
#include <hip/hip_runtime.h>
#include <cstdint>

#define D_EDGES 64
#define K_KEEP  32

// Bit-exact replication of numpy's SIMD f32 exp (Cephes-based, max ULP 2.52).
// Verified: absmax 0 vs the np reference (rounds 3 & 4).
__device__ __forceinline__ float np_expf(float x) {
    const float log2e     = 1.44269504088896341f;
    const float cvt_magic = 12582912.0f;            // 1.5 * 2^23 RNE trick
    const float neg_ln2hi = -0.693359375f;
    const float neg_ln2lo = 2.12194440e-4f;
    const float p0 = 1.9875691500E-4f;
    const float p1 = 1.3981999507E-3f;
    const float p2 = 8.3334519073E-3f;
    const float p3 = 4.1665795894E-2f;
    const float p4 = 1.6666665459E-1f;
    const float p5 = 5.0000001201E-1f;

    float q = fmaf(x, log2e, cvt_magic);
    q -= cvt_magic;
    x = fmaf(q, neg_ln2hi, x);
    x = fmaf(q, neg_ln2lo, x);
    float x2 = x * x;
    float poly = fmaf(p0, x, p1);
    poly = fmaf(poly, x, p2);
    poly = fmaf(poly, x, p3);
    poly = fmaf(poly, x, p4);
    poly = fmaf(poly, x, p5);
    poly = fmaf(poly, x2, x);
    poly = poly + 1.0f;
    return ldexpf(poly, (int)q);
}

__device__ __forceinline__ float sigmoid_np(float x) {
    float e = np_expf(-x);
    return 1.0f / (1.0f + e);
}

// ---- xor-shuffle of a u64, cheapest HW path per distance (verified R4) ----
template <int CTRL>
__device__ __forceinline__ unsigned long long xor_dpp_u64(unsigned long long v) {
    int lo = (int)(unsigned)v;
    int hi = (int)(v >> 32);
    lo = __builtin_amdgcn_update_dpp(lo, lo, CTRL, 0xF, 0xF, true);
    hi = __builtin_amdgcn_update_dpp(hi, hi, CTRL, 0xF, 0xF, true);
    return ((unsigned long long)(unsigned)hi << 32) | (unsigned)lo;
}

template <int OFF>
__device__ __forceinline__ unsigned long long xor_swz_u64(unsigned long long v) {
    int lo = (int)(unsigned)v;
    int hi = (int)(v >> 32);
    lo = __builtin_amdgcn_ds_swizzle(lo, OFF);
    hi = __builtin_amdgcn_ds_swizzle(hi, OFF);
    return ((unsigned long long)(unsigned)hi << 32) | (unsigned)lo;
}

template <int J>
__device__ __forceinline__ unsigned long long xorshfl_u64(unsigned long long v) {
    if constexpr (J == 1)       return xor_dpp_u64<0xB1>(v);    // quad_perm [1,0,3,2]
    else if constexpr (J == 2)  return xor_dpp_u64<0x4E>(v);    // quad_perm [2,3,0,1]
    else if constexpr (J == 4)  return xor_swz_u64<0x101F>(v);  // swizzle xor4
    else if constexpr (J == 8)  return xor_dpp_u64<0x128>(v);   // row_ror:8 == xor8
    else if constexpr (J == 16) return xor_swz_u64<0x401F>(v);  // swizzle xor16
    else {                                                      // J == 32
        int lo = (int)(unsigned)v;
        int hi = (int)(v >> 32);
        lo = __shfl_xor(lo, 32, 64);
        hi = __shfl_xor(hi, 32, 64);
        return ((unsigned long long)(unsigned)hi << 32) | (unsigned)lo;
    }
}

// One bitonic compare-exchange substage, descending overall.
// Semantics identical to the verified round-3/4 loop body.
template <int K, int J>
__device__ __forceinline__ void stage(unsigned long long& key, int lane) {
    unsigned long long other = xorshfl_u64<J>(key);
    const bool dir = ((lane & J) == 0) == ((lane & K) == 0);
    key = ((key > other) != dir) ? other : key;
}

// Single fused kernel: one wave (64 lanes) per segment of D=64 edges.
// Key = (f32bits(sim) << 6) | (63 ^ lane); descending bitonic sort; lanes
// 0..31 emit the top-K. dst is segment-constant (edges grouped by dest),
// so sd is computed once via the scalar path and row 1 of the output is
// just dst. All indexing fits in 32 bits (E = 2^24).
__global__ __launch_bounds__(256)
void topk_kernel(const int* __restrict__ edge_index,   // [2, E]
                 const float* __restrict__ logits,
                 int* __restrict__ out,                // [2, nseg*K]
                 int E, int nseg, int outHalf) {
    const int tid = threadIdx.x;
    const int lane = tid & 63;
    const int w = (blockIdx.x << 2) | (tid >> 6);   // 4 waves/block
    if (w >= nseg) return;
    const int e = (w << 6) | lane;

    int src = edge_index[e];
    int dst = edge_index[E + e];

    float ss = sigmoid_np(logits[src]);             // per-edge gather (L2-hot)
    int dst0 = __builtin_amdgcn_readfirstlane(dst); // wave-uniform -> s_load
    float sd = sigmoid_np(logits[dst0]);
    float sim = 1.0f - fabsf(ss - sd);              // matches np f32 pipeline

    unsigned long long key =
        ((unsigned long long)__float_as_uint(sim) << 6) |
        (unsigned long long)(lane ^ 63);

    // Full 64-lane bitonic sort, descending; j=1,2,8 on DPP (VALU),
    // j=4,16 on ds_swizzle, j=32 on bpermute.
    stage<2, 1>(key, lane);
    stage<4, 2>(key, lane);   stage<4, 1>(key, lane);
    stage<8, 4>(key, lane);   stage<8, 2>(key, lane);   stage<8, 1>(key, lane);
    stage<16, 8>(key, lane);  stage<16, 4>(key, lane);  stage<16, 2>(key, lane);
    stage<16, 1>(key, lane);
    stage<32, 16>(key, lane); stage<32, 8>(key, lane);  stage<32, 4>(key, lane);
    stage<32, 2>(key, lane);  stage<32, 1>(key, lane);
    stage<64, 32>(key, lane); stage<64, 16>(key, lane); stage<64, 8>(key, lane);
    stage<64, 4>(key, lane);  stage<64, 2>(key, lane);  stage<64, 1>(key, lane);

    // Lane r (r < K) holds rank-r key; pull the owning lane's src.
    int origLane = ((int)(key & 63)) ^ 63;
    int sel_src = __shfl(src, origLane, 64);

    if (lane < K_KEEP) {
        int base = (w << 5) | lane;
        out[base] = sel_src;           // row 0: selected src
        out[outHalf + base] = dst;     // row 1: dst (segment-constant)
    }
}

extern "C" void kernel_launch(void* const* d_in, const int* in_sizes, int n_in,
                              void* d_out, int out_size, void* d_ws, size_t ws_size,
                              hipStream_t stream) {
    const float* logits = (const float*)d_in[0];
    const int* edge_index = (const int*)d_in[1];
    int E = in_sizes[1] / 2;             // 2^24, fits int
    int nseg = E / D_EDGES;              // 2^18
    int outHalf = nseg * K_KEEP;         // 2^23
    int* out = (int*)d_out;

    int blocks = (nseg + 3) / 4;         // 4 waves (segments) per 256-thr block
    topk_kernel<<<blocks, 256, 0, stream>>>(edge_index, logits, out,
                                            E, nseg, outHalf);
}

// Round 6
// 283.360 us; speedup vs baseline: 1.0052x; 1.0052x over previous
//
#include <hip/hip_runtime.h>
#include <cstdint>

#define D_EDGES 64
#define K_KEEP  32

// Bit-exact replication of numpy's SIMD f32 exp (Cephes-based, max ULP 2.52).
// Verified: absmax 0 vs the np reference (rounds 3,4,5).
__device__ __forceinline__ float np_expf(float x) {
    const float log2e     = 1.44269504088896341f;
    const float cvt_magic = 12582912.0f;            // 1.5 * 2^23 RNE trick
    const float neg_ln2hi = -0.693359375f;
    const float neg_ln2lo = 2.12194440e-4f;
    const float p0 = 1.9875691500E-4f;
    const float p1 = 1.3981999507E-3f;
    const float p2 = 8.3334519073E-3f;
    const float p3 = 4.1665795894E-2f;
    const float p4 = 1.6666665459E-1f;
    const float p5 = 5.0000001201E-1f;

    float q = fmaf(x, log2e, cvt_magic);
    q -= cvt_magic;
    x = fmaf(q, neg_ln2hi, x);
    x = fmaf(q, neg_ln2lo, x);
    float x2 = x * x;
    float poly = fmaf(p0, x, p1);
    poly = fmaf(poly, x, p2);
    poly = fmaf(poly, x, p3);
    poly = fmaf(poly, x, p4);
    poly = fmaf(poly, x, p5);
    poly = fmaf(poly, x2, x);
    poly = poly + 1.0f;
    return ldexpf(poly, (int)q);
}

__device__ __forceinline__ float sigmoid_np(float x) {
    float e = np_expf(-x);
    return 1.0f / (1.0f + e);
}

__global__ void sigmoid_kernel(const float* __restrict__ logits,
                               float* __restrict__ s, int n) {
    int i = blockIdx.x * blockDim.x + threadIdx.x;
    if (i < n) s[i] = sigmoid_np(logits[i]);
}

// ---------------- 32-bit fast-path shuffle helpers ----------------
template <int CTRL>
__device__ __forceinline__ unsigned xor_dpp_u32(unsigned v) {
    return (unsigned)__builtin_amdgcn_update_dpp((int)v, (int)v, CTRL, 0xF, 0xF, true);
}

template <int J>
__device__ __forceinline__ unsigned xorshfl_u32(unsigned v, int addr32) {
    if constexpr (J == 1)       return xor_dpp_u32<0xB1>(v);    // quad_perm [1,0,3,2]
    else if constexpr (J == 2)  return xor_dpp_u32<0x4E>(v);    // quad_perm [2,3,0,1]
    else if constexpr (J == 4)  return (unsigned)__builtin_amdgcn_ds_swizzle((int)v, 0x101F);
    else if constexpr (J == 8)  return xor_dpp_u32<0x128>(v);   // row_ror:8 == xor8
    else if constexpr (J == 16) return (unsigned)__builtin_amdgcn_ds_swizzle((int)v, 0x401F);
    else                        return (unsigned)__builtin_amdgcn_ds_bpermute(addr32, (int)v);
}

// One substage: key = dir ? max(key,other) : min(key,other).
// Equivalent to the verified cmp/select form (ties impossible: lane bits).
template <int J>
__device__ __forceinline__ void stage32(unsigned& key, bool dir, int addr32) {
    unsigned other = xorshfl_u32<J>(key, addr32);
    unsigned mx = (key > other) ? key : other;
    unsigned mn = (key > other) ? other : key;
    key = dir ? mx : mn;
}

// ---------------- u64 slow-path (verified rounds 3-5) ----------------
template <int CTRL>
__device__ __forceinline__ unsigned long long xor_dpp_u64(unsigned long long v) {
    int lo = (int)(unsigned)v;
    int hi = (int)(v >> 32);
    lo = __builtin_amdgcn_update_dpp(lo, lo, CTRL, 0xF, 0xF, true);
    hi = __builtin_amdgcn_update_dpp(hi, hi, CTRL, 0xF, 0xF, true);
    return ((unsigned long long)(unsigned)hi << 32) | (unsigned)lo;
}

template <int OFF>
__device__ __forceinline__ unsigned long long xor_swz_u64(unsigned long long v) {
    int lo = (int)(unsigned)v;
    int hi = (int)(v >> 32);
    lo = __builtin_amdgcn_ds_swizzle(lo, OFF);
    hi = __builtin_amdgcn_ds_swizzle(hi, OFF);
    return ((unsigned long long)(unsigned)hi << 32) | (unsigned)lo;
}

template <int J>
__device__ __forceinline__ unsigned long long xorshfl_u64(unsigned long long v) {
    if constexpr (J == 1)       return xor_dpp_u64<0xB1>(v);
    else if constexpr (J == 2)  return xor_dpp_u64<0x4E>(v);
    else if constexpr (J == 4)  return xor_swz_u64<0x101F>(v);
    else if constexpr (J == 8)  return xor_dpp_u64<0x128>(v);
    else if constexpr (J == 16) return xor_swz_u64<0x401F>(v);
    else {
        int lo = (int)(unsigned)v;
        int hi = (int)(v >> 32);
        lo = __shfl_xor(lo, 32, 64);
        hi = __shfl_xor(hi, 32, 64);
        return ((unsigned long long)(unsigned)hi << 32) | (unsigned)lo;
    }
}

template <int K, int J>
__device__ __forceinline__ void stage64(unsigned long long& key, int lane) {
    unsigned long long other = xorshfl_u64<J>(key);
    const bool dir = ((lane & J) == 0) == ((lane & K) == 0);
    key = ((key > other) != dir) ? other : key;
}

// One wave per segment of D=64 edges. Descending bitonic sort of
// (sim, tie->lower-index) keys; lane r<32 emits rank-r src, lanes 32-63
// emit dst (segment-constant: edges grouped by dest).
__global__ __launch_bounds__(256)
void topk_kernel(const int* __restrict__ edge_index,   // [2, E]
                 const float* __restrict__ stab,       // sigmoid table [N]
                 int* __restrict__ out,                // [2, nseg*K]
                 int E, int nseg, int outHalf) {
    const int tid = threadIdx.x;
    const int lane = tid & 63;
    const int w = (blockIdx.x << 2) | (tid >> 6);   // 4 waves/block
    if (w >= nseg) return;
    const int e = (w << 6) | lane;

    int src = edge_index[e];
    int dst = edge_index[E + e];

    float ss = stab[src];                            // L2-hot 1MB gather
    float sd = stab[__builtin_amdgcn_readfirstlane(dst)];  // scalar path
    float sim = 1.0f - fabsf(ss - sd);               // np f32 pipeline

    // Hoisted lane-bit masks (SGPR-pair lane masks; per-stage dir = s_xnor).
    const bool b1  = (lane & 1)  == 0;
    const bool b2  = (lane & 2)  == 0;
    const bool b4  = (lane & 4)  == 0;
    const bool b8  = (lane & 8)  == 0;
    const bool b16 = (lane & 16) == 0;
    const bool b32 = (lane & 32) == 0;
    const int addr32 = (lane ^ 32) << 2;             // bpermute addr for j=32

    int origLane;
    // Fast path: all sims in [0.0625, 1] -> lossless 32-bit key
    //   key = ((bits(sim) - 0x3D800000) << 6) | (lane^63)
    // strictly order-isomorphic to the verified u64 key. Violation needs a
    // sigmoid pair spanning >0.9375 => ~1 wave per run takes the slow path.
    if (__all(sim >= 0.0625f)) {
        unsigned kb = __float_as_uint(sim);
        unsigned key = ((kb - 0x3D800000u) << 6) | (unsigned)(lane ^ 63);

        stage32<1>(key, b1 == b2, addr32);
        stage32<2>(key, b2 == b4, addr32);  stage32<1>(key, b1 == b4, addr32);
        stage32<4>(key, b4 == b8, addr32);  stage32<2>(key, b2 == b8, addr32);
        stage32<1>(key, b1 == b8, addr32);
        stage32<8>(key, b8 == b16, addr32); stage32<4>(key, b4 == b16, addr32);
        stage32<2>(key, b2 == b16, addr32); stage32<1>(key, b1 == b16, addr32);
        stage32<16>(key, b16 == b32, addr32); stage32<8>(key, b8 == b32, addr32);
        stage32<4>(key, b4 == b32, addr32);   stage32<2>(key, b2 == b32, addr32);
        stage32<1>(key, b1 == b32, addr32);
        stage32<32>(key, b32, addr32); stage32<16>(key, b16, addr32);
        stage32<8>(key, b8, addr32);   stage32<4>(key, b4, addr32);
        stage32<2>(key, b2, addr32);   stage32<1>(key, b1, addr32);

        origLane = ((int)key & 63) ^ 63;
    } else {
        // Verified u64 network (rounds 3-5, absmax 0).
        unsigned long long key =
            ((unsigned long long)__float_as_uint(sim) << 6) |
            (unsigned long long)(lane ^ 63);
        stage64<2, 1>(key, lane);
        stage64<4, 2>(key, lane);   stage64<4, 1>(key, lane);
        stage64<8, 4>(key, lane);   stage64<8, 2>(key, lane);   stage64<8, 1>(key, lane);
        stage64<16, 8>(key, lane);  stage64<16, 4>(key, lane);  stage64<16, 2>(key, lane);
        stage64<16, 1>(key, lane);
        stage64<32, 16>(key, lane); stage64<32, 8>(key, lane);  stage64<32, 4>(key, lane);
        stage64<32, 2>(key, lane);  stage64<32, 1>(key, lane);
        stage64<64, 32>(key, lane); stage64<64, 16>(key, lane); stage64<64, 8>(key, lane);
        stage64<64, 4>(key, lane);  stage64<64, 2>(key, lane);  stage64<64, 1>(key, lane);
        origLane = ((int)(key & 63)) ^ 63;
    }

    // Lane r (r<32) holds rank-r; pull the owning lane's src.
    int sel_src = __builtin_amdgcn_ds_bpermute(origLane << 2, src);

    // One store per lane: lanes 0-31 write row 0 (selected src),
    // lanes 32-63 write row 1 (dst, segment-constant).
    int col = lane & 31;
    int base = (w << 5) | col;
    bool hiHalf = lane >= 32;
    out[hiHalf ? (outHalf + base) : base] = hiHalf ? dst : sel_src;
}

extern "C" void kernel_launch(void* const* d_in, const int* in_sizes, int n_in,
                              void* d_out, int out_size, void* d_ws, size_t ws_size,
                              hipStream_t stream) {
    const float* logits = (const float*)d_in[0];
    const int* edge_index = (const int*)d_in[1];
    int N = in_sizes[0];
    int E = in_sizes[1] / 2;             // 2^24, fits int
    int nseg = E / D_EDGES;              // 2^18
    int outHalf = nseg * K_KEEP;         // 2^23
    int* out = (int*)d_out;

    float* stab = (float*)d_ws;          // 1 MB sigmoid table
    sigmoid_kernel<<<(N + 255) / 256, 256, 0, stream>>>(logits, stab, N);

    int blocks = (nseg + 3) / 4;         // 4 waves (segments) per 256-thr block
    topk_kernel<<<blocks, 256, 0, stream>>>(edge_index, stab, out,
                                            E, nseg, outHalf);
}